// Round 10
// baseline (576.965 us; speedup 1.0000x reference)
//
#include <hip/hip_runtime.h>
#include <math.h>

#define S_LEN 2048
#define HID_DIM 2048
#define NH 16
#define NKVH 4
#define HD 128
#define QD (NH*HD)    // 2048
#define KD (NKVH*HD)  // 512
#define NQKV 3072     // Q(2048) | K(512) | V(512)

typedef _Float16 half8_t __attribute__((ext_vector_type(8)));
typedef _Float16 half4_t __attribute__((ext_vector_type(4)));
typedef float f32x4 __attribute__((ext_vector_type(4)));

#define BM 128
#define BN 128
#define BK 32

typedef const __attribute__((address_space(1))) char gas_char;
typedef __attribute__((address_space(3))) char las_char;
#define GL16(gp, lp) __builtin_amdgcn_global_load_lds((gas_char*)(gp), (las_char*)(lp), 16, 0, 0)

// ---------------------------------------------------------------------------
// f16-plane MFMA GEMM, NT (verified rounds 5-9). Passes: Ahi*Bhi
// [+ Ahi*Blo if LB==2][+ Alo*Bhi if LA==2]. AF32: A f32 -> exact codes.
// qmode: 0 f32 store; 1 sym code f16; 2 asym code f16; 3 sym, scale by n0.
// ---------------------------------------------------------------------------
template<int LA, int LB, bool AF32>
__global__ __launch_bounds__(256)
void gemm_f16(const void* __restrict__ Ap, const _Float16* __restrict__ Alo,
              int lda, long long strA,
              const _Float16* __restrict__ Bhi, const _Float16* __restrict__ Blo,
              int ldb, long long strB, int divB,
              void* __restrict__ Cp, int ldc, long long strC,
              int K, float scale_c, const float* sc1, const float* sc2,
              const float* preAp,
              int qmode, const float* q1, const float* q2, const float* q3,
              int causal, int triK)
{
    int bz = blockIdx.z;
    int m0 = blockIdx.y * BM, n0 = blockIdx.x * BN;
    if (causal && n0 > m0 + (BM - 1)) return;
    int Keff = K;
    if (triK && (m0 + BM) < Keff) Keff = m0 + BM;

    const _Float16* Ahi = AF32 ? nullptr : (const _Float16*)Ap + bz * strA;
    const _Float16* AloP = (LA == 2) ? Alo + bz * strA : nullptr;
    const float* Af = AF32 ? (const float*)Ap + bz * strA : nullptr;
    const _Float16* BhiP = Bhi + (long long)(bz / divB) * strB;
    const _Float16* BloP = (LB == 2) ? Blo + (long long)(bz / divB) * strB : nullptr;
    float* Cf = (float*)Cp + bz * strC;
    _Float16* Ch = (_Float16*)Cp + bz * strC;

    float preA = 1.f;
    if (AF32) preA = 1.f / fabsf(preAp[0]);

    __shared__ _Float16 lds[(LA + LB) * 4096];
    _Float16* As0 = lds;
    _Float16* As1 = lds + 4096;
    _Float16* Bs0 = lds + LA * 4096;
    _Float16* Bs1 = lds + (LA + 1) * 4096;

    int t = threadIdx.x;
    int srow = t >> 2;
    int gsw = (srow >> 1) & 3;
    int gc = ((t & 3) ^ gsw) * 8;
    int w = t >> 6, lane = t & 63;
    int wm = (w >> 1) * 64, wn = (w & 1) * 64;
    int lr = lane & 15, lg = lane >> 4;
    int fco = ((lg ^ ((lr >> 1) & 3))) * 8;

    f32x4 acc[4][4];
    #pragma unroll
    for (int i = 0; i < 4; ++i)
        #pragma unroll
        for (int j = 0; j < 4; ++j)
            acc[i][j] = (f32x4){0.f, 0.f, 0.f, 0.f};

    for (int k0 = 0; k0 < Keff; k0 += BK) {
        f32x4 aF[2][2];
        if constexpr (AF32) {
            #pragma unroll
            for (int rep = 0; rep < 2; ++rep) {
                long long ai = (long long)(m0 + rep * 64 + srow) * lda + k0 + gc;
                aF[rep][0] = *(const f32x4*)&Af[ai];
                aF[rep][1] = *(const f32x4*)&Af[ai + 4];
            }
        }
        __syncthreads();
        #pragma unroll
        for (int rep = 0; rep < 2; ++rep) {
            int row = rep * 64 + srow;
            int lo = rep * 2048 + t * 8;
            if constexpr (!AF32) {
                long long ai = (long long)(m0 + row) * lda + k0 + gc;
                GL16(Ahi + ai, As0 + lo);
                if constexpr (LA == 2) GL16(AloP + ai, As1 + lo);
            }
            long long bi = (long long)(n0 + row) * ldb + k0 + gc;
            GL16(BhiP + bi, Bs0 + lo);
            if constexpr (LB == 2) GL16(BloP + bi, Bs1 + lo);
        }
        if constexpr (AF32) {
            #pragma unroll
            for (int rep = 0; rep < 2; ++rep) {
                half8_t h;
                #pragma unroll
                for (int e = 0; e < 4; ++e) {
                    h[e]     = (_Float16)(aF[rep][0][e] * preA);
                    h[e + 4] = (_Float16)(aF[rep][1][e] * preA);
                }
                *(half8_t*)&As0[rep * 2048 + t * 8] = h;
            }
        }
        __syncthreads();

        half8_t a0[4], b0[4];
        #pragma unroll
        for (int i = 0; i < 4; ++i) a0[i] = *(const half8_t*)&As0[(wm + i*16 + lr) * 32 + fco];
        #pragma unroll
        for (int j = 0; j < 4; ++j) b0[j] = *(const half8_t*)&Bs0[(wn + j*16 + lr) * 32 + fco];
        #pragma unroll
        for (int i = 0; i < 4; ++i)
            #pragma unroll
            for (int j = 0; j < 4; ++j)
                acc[i][j] = __builtin_amdgcn_mfma_f32_16x16x32_f16(a0[i], b0[j], acc[i][j], 0, 0, 0);
        if constexpr (LB == 2) {
            half8_t b1[4];
            #pragma unroll
            for (int j = 0; j < 4; ++j) b1[j] = *(const half8_t*)&Bs1[(wn + j*16 + lr) * 32 + fco];
            #pragma unroll
            for (int i = 0; i < 4; ++i)
                #pragma unroll
                for (int j = 0; j < 4; ++j)
                    acc[i][j] = __builtin_amdgcn_mfma_f32_16x16x32_f16(a0[i], b1[j], acc[i][j], 0, 0, 0);
        }
        if constexpr (LA == 2) {
            half8_t a1[4];
            #pragma unroll
            for (int i = 0; i < 4; ++i) a1[i] = *(const half8_t*)&As1[(wm + i*16 + lr) * 32 + fco];
            #pragma unroll
            for (int i = 0; i < 4; ++i)
                #pragma unroll
                for (int j = 0; j < 4; ++j)
                    acc[i][j] = __builtin_amdgcn_mfma_f32_16x16x32_f16(a1[i], b0[j], acc[i][j], 0, 0, 0);
        }
    }

    float se = scale_c;
    if (sc1) se *= fabsf(sc1[0]);
    if (sc2) se *= fabsf(sc2[0]);
    float sv = 1.f;
    if (qmode == 3) {
        const float* sp = (n0 < 2048) ? q1 : ((n0 < 2560) ? q2 : q3);
        sv = fabsf(sp[0]);
        qmode = 1;
    } else if (qmode) {
        sv = fabsf(q1[0]);
    }

    #pragma unroll
    for (int i = 0; i < 4; ++i)
        #pragma unroll
        for (int j = 0; j < 4; ++j)
            #pragma unroll
            for (int r = 0; r < 4; ++r) {
                long long row = m0 + wm + i * 16 + lg * 4 + r;
                long long col = n0 + wn + j * 16 + lr;
                float v = acc[i][j][r] * se;
                if (qmode == 0) {
                    Cf[row * (long long)ldc + col] = v;
                } else if (qmode == 1) {
                    float u = rintf(fminf(fmaxf(v / sv, -128.f), 127.f));
                    Ch[row * (long long)ldc + col] = (_Float16)u;
                } else {
                    float u = rintf(fminf(fmaxf(v / sv, 0.f), 255.f));
                    Ch[row * (long long)ldc + col] = (_Float16)u;
                }
            }
}

// ---------------------------------------------------------------------------
// LDS-free direct-fragment scores GEMM (K=HD=128, NT, f16 hi/lo planes,
// 3 passes) + raw f32 score store + PSM partial (max, sumexp) epilogue.
// No barriers, no LDS: each lane loads its MFMA fragments straight from
// global (row-contiguous 16B chunks); tiles are L2-shared across waves.
// Math identical to the LDS path -> bit-identical scores.
// ---------------------------------------------------------------------------
__global__ __launch_bounds__(256)
void scores_direct(const _Float16* __restrict__ qhi, const _Float16* __restrict__ qlo,
                   const _Float16* __restrict__ khi, const _Float16* __restrict__ klo,
                   float* __restrict__ attn, float* __restrict__ pml,
                   const float* sq_p, const float* sk_p)
{
    int m0 = blockIdx.y * BM, n0 = blockIdx.x * BN;
    if (n0 > m0 + (BM - 1)) return;
    int h = blockIdx.z;

    const _Float16* Qh = qhi + (long long)h * S_LEN * HD;
    const _Float16* Ql = qlo + (long long)h * S_LEN * HD;
    const _Float16* Kh = khi + (long long)(h >> 2) * S_LEN * HD;
    const _Float16* Kl = klo + (long long)(h >> 2) * S_LEN * HD;
    float* S = attn + (long long)h * S_LEN * S_LEN;

    float se = fabsf(sq_p[0]) * fabsf(sk_p[0]) * 0.08838834764831845f;

    int t = threadIdx.x;
    int w = t >> 6, lane = t & 63;
    int wm = (w >> 1) * 64, wn = (w & 1) * 64;
    int lr = lane & 15, lg = lane >> 4;

    f32x4 acc[4][4];
    #pragma unroll
    for (int i = 0; i < 4; ++i)
        #pragma unroll
        for (int j = 0; j < 4; ++j)
            acc[i][j] = (f32x4){0.f, 0.f, 0.f, 0.f};

    #pragma unroll 1
    for (int ks = 0; ks < 4; ++ks) {
        int kc = ks * 32 + lg * 8;
        half8_t a0[4], a1[4], b0[4], b1[4];
        #pragma unroll
        for (int i = 0; i < 4; ++i) {
            long long ai = (long long)(m0 + wm + i * 16 + lr) * HD + kc;
            a0[i] = *(const half8_t*)&Qh[ai];
            a1[i] = *(const half8_t*)&Ql[ai];
        }
        #pragma unroll
        for (int j = 0; j < 4; ++j) {
            long long bi = (long long)(n0 + wn + j * 16 + lr) * HD + kc;
            b0[j] = *(const half8_t*)&Kh[bi];
            b1[j] = *(const half8_t*)&Kl[bi];
        }
        #pragma unroll
        for (int i = 0; i < 4; ++i)
            #pragma unroll
            for (int j = 0; j < 4; ++j)
                acc[i][j] = __builtin_amdgcn_mfma_f32_16x16x32_f16(a0[i], b0[j], acc[i][j], 0, 0, 0);
        #pragma unroll
        for (int i = 0; i < 4; ++i)
            #pragma unroll
            for (int j = 0; j < 4; ++j)
                acc[i][j] = __builtin_amdgcn_mfma_f32_16x16x32_f16(a0[i], b1[j], acc[i][j], 0, 0, 0);
        #pragma unroll
        for (int i = 0; i < 4; ++i)
            #pragma unroll
            for (int j = 0; j < 4; ++j)
                acc[i][j] = __builtin_amdgcn_mfma_f32_16x16x32_f16(a1[i], b0[j], acc[i][j], 0, 0, 0);
    }

    int cb64 = (n0 + wn) >> 6;
    #pragma unroll
    for (int i = 0; i < 4; ++i)
        #pragma unroll
        for (int r = 0; r < 4; ++r) {
            int row = m0 + wm + i * 16 + lg * 4 + r;
            float vv[4];
            float mloc = -INFINITY;
            #pragma unroll
            for (int j = 0; j < 4; ++j) {
                int col = n0 + wn + j * 16 + lr;
                float v = acc[i][j][r] * se;
                S[(long long)row * S_LEN + col] = v;
                vv[j] = (col <= row) ? v : -INFINITY;
                mloc = fmaxf(mloc, vv[j]);
            }
            #pragma unroll
            for (int o = 1; o < 16; o <<= 1) mloc = fmaxf(mloc, __shfl_xor(mloc, o));
            float sloc = 0.f;
            #pragma unroll
            for (int j = 0; j < 4; ++j) sloc += expf(vv[j] - mloc);
            #pragma unroll
            for (int o = 1; o < 16; o <<= 1) sloc += __shfl_xor(sloc, o);
            if (lr == 0) {
                long long idx = (((long long)h * S_LEN + row) * 32 + cb64) * 2;
                pml[idx] = mloc;
                pml[idx + 1] = sloc;
            }
        }
}

// ---------------------------------------------------------------------------
// Reduce per-64col partials -> per-row (max, sum)
// ---------------------------------------------------------------------------
__global__ __launch_bounds__(256)
void reduce_ml(const float* __restrict__ pml, float* __restrict__ fml)
{
    int id = blockIdx.x * 256 + threadIdx.x;   // h*S + r
    int r = id & (S_LEN - 1);
    int nb = (r >> 6) + 1;
    float m = -INFINITY, l = 0.f;
    const float* p = pml + (long long)id * 64;
    for (int cb = 0; cb < nb; ++cb) {
        float mp = p[cb * 2], lp = p[cb * 2 + 1];
        float mn = fmaxf(m, mp);
        l = l * expf(m - mn) + lp * expf(mp - mn);
        m = mn;
    }
    fml[id * 2] = m;
    fml[id * 2 + 1] = l;
}

// ---------------------------------------------------------------------------
// Streaming softmax finalize + LSQ(asym) in place; reads only the causal
// region, writes full row incl. zero upper triangle.
// ---------------------------------------------------------------------------
__global__ __launch_bounds__(256)
void finalize_quant(float* __restrict__ attn, const float* __restrict__ fml,
                    const float* __restrict__ s_at_p)
{
    int row = blockIdx.x;            // h*S + q
    int q = row & (S_LEN - 1);
    float* p = attn + (long long)row * S_LEN;
    float m = fml[row * 2];
    float l = fml[row * 2 + 1];
    float sa = fabsf(s_at_p[0]);
    int t = threadIdx.x;
    int n4 = (q + 4) & ~3;           // first x4 boundary past q
    for (int c = t * 4; c < n4; c += 1024) {
        f32x4 v = *(const f32x4*)&p[c];
        f32x4 o;
        #pragma unroll
        for (int e = 0; e < 4; ++e) {
            float u = 0.f;
            if (c + e <= q) {
                float pr = expf(v[e] - m) / l;
                u = rintf(fminf(fmaxf(pr / sa, 0.f), 255.f));
            }
            o[e] = u * sa;
        }
        *(f32x4*)&p[c] = o;
    }
    f32x4 z = (f32x4){0.f, 0.f, 0.f, 0.f};
    for (int c = n4 + t * 4; c < S_LEN; c += 1024)
        *(f32x4*)&p[c] = z;
}

// ---------------------------------------------------------------------------
// f32 -> f16 hi/lo split
// ---------------------------------------------------------------------------
__global__ void split_f16(const float* __restrict__ in, _Float16* __restrict__ hi,
                          _Float16* __restrict__ lo, int n4)
{
    int i = blockIdx.x * 256 + threadIdx.x;
    if (i >= n4) return;
    f32x4 v = ((const f32x4*)in)[i];
    half4_t h, l;
    #pragma unroll
    for (int e = 0; e < 4; ++e) {
        h[e] = (_Float16)v[e];
        l[e] = (_Float16)(v[e] - (float)h[e]);
    }
    ((half4_t*)hi)[i] = h;
    ((half4_t*)lo)[i] = l;
}

// ---------------------------------------------------------------------------
// RoPE on integer codes (strided source) -> hi/lo f16 planes: [nh][S][HD]
// ---------------------------------------------------------------------------
__global__ void rope_f16(const _Float16* __restrict__ codes, int ldc_, int colOff,
                         const float* __restrict__ cosT,
                         const float* __restrict__ sinT,
                         _Float16* __restrict__ ohi, _Float16* __restrict__ olo, int nh)
{
    long long idx = (long long)blockIdx.x * 256 + threadIdx.x;
    int d = idx & (HD - 1);
    long long tt = idx >> 7;     // s*nh + h
    int h = (int)(tt % nh);
    int s = (int)(tt / nh);
    long long base = (long long)s * ldc_ + colOff + h * HD;
    float x = (float)codes[base + d];
    float other = (d < 64) ? -(float)codes[base + d + 64] : (float)codes[base + d - 64];
    float o = x * cosT[s * HD + d] + other * sinT[s * HD + d];
    _Float16 hf = (_Float16)o;
    long long oi = ((long long)h * S_LEN + s) * HD + d;
    ohi[oi] = hf;
    olo[oi] = (_Float16)(o - (float)hf);
}

// ---------------------------------------------------------------------------
// v codes transpose: qkvcode[S][3072] cols 2560.. -> vT [kvh][HD][S]
// ---------------------------------------------------------------------------
__global__ __launch_bounds__(256)
void transpose_vf16(const _Float16* __restrict__ in, _Float16* __restrict__ outp)
{
    __shared__ _Float16 tile[64][72];
    int s0 = blockIdx.x * 64, d0 = blockIdx.y * 64, h = blockIdx.z;
    int t = threadIdx.x;
    int rr = t >> 4, cc = (t & 15) * 4;
    #pragma unroll
    for (int r = 0; r < 4; ++r) {
        half4_t v = *(const half4_t*)&in[(long long)(s0 + rr + 16*r) * NQKV + 2560 + h * HD + d0 + cc];
        *(half4_t*)&tile[rr + 16*r][cc] = v;
    }
    __syncthreads();
    #pragma unroll
    for (int r = 0; r < 4; ++r) {
        int dr = rr + 16 * r;
        half4_t o = { tile[cc+0][dr], tile[cc+1][dr], tile[cc+2][dr], tile[cc+3][dr] };
        *(half4_t*)&outp[((long long)h * HD + d0 + dr) * S_LEN + s0 + cc] = o;
    }
}

extern "C" void kernel_launch(void* const* d_in, const int* in_sizes, int n_in,
                              void* d_out, int out_size, void* d_ws, size_t ws_size,
                              hipStream_t stream)
{
    const float* hs    = (const float*)d_in[0];
    const float* Wq    = (const float*)d_in[1];
    const float* Wk    = (const float*)d_in[2];
    const float* Wv    = (const float*)d_in[3];
    const float* Wo    = (const float*)d_in[4];
    const float* s_q   = (const float*)d_in[5];
    const float* s_k   = (const float*)d_in[6];
    const float* s_v   = (const float*)d_in[7];
    const float* s_at  = (const float*)d_in[8];
    const float* s_out = (const float*)d_in[9];
    const float* cosT  = (const float*)d_in[10];
    const float* sinT  = (const float*)d_in[11];
    // d_in[12] = attention_mask: pure causal, applied structurally.

    float* out  = (float*)d_out;                         // [S][2048]
    float* attn = out + (long long)S_LEN * HID_DIM;      // [16][S][S]

    const long long M1 = 1LL * 1024 * 1024;
    const long long M4 = 4LL * M1;
    const long long M6 = 6LL * M1;

    // ws (46 MB): planes that must survive past the scores GEMM.
    _Float16* wsh   = (_Float16*)d_ws;
    _Float16* qr_hi = wsh;            // 4M
    _Float16* qr_lo = qr_hi + M4;     // 4M
    _Float16* kr_hi = qr_lo + M4;     // 1M
    _Float16* kr_lo = kr_hi + M1;     // 1M
    _Float16* vT    = kr_lo + M1;     // 1M
    _Float16* ao    = vT + M1;        // 4M
    _Float16* Wo_hi = ao + M4;        // 4M
    _Float16* Wo_lo = Wo_hi + M4;     // 4M

    // Pre-scores scratch parked inside the attn region (consumed before
    // the scores GEMM overwrites it).
    _Float16* sc      = (_Float16*)attn;
    _Float16* hs_hi   = sc;             // 4M
    _Float16* hs_lo   = hs_hi + M4;
    _Float16* Whi     = hs_lo + M4;     // [3072][2048] = 6M
    _Float16* Wlo     = Whi + M6;
    _Float16* qkvcode = Wlo + M6;       // [S][3072] = 6M

    // Softmax stats parked in the 'out' region (out written only at the end).
    float* pml = out;                       // [NH][S][32][2] = 2M f32
    float* fml = out + 2LL * 1024 * 1024;   // [NH][S][2]

    dim3 blk(256);

    // 0) one-shot f32 -> f16 hi/lo splits (W planes stacked Q|K|V)
    split_f16<<<4096, blk, 0, stream>>>(hs, hs_hi, hs_lo, 1024*1024);
    split_f16<<<4096, blk, 0, stream>>>(Wq, Whi, Wlo, 1024*1024);
    split_f16<<<1024, blk, 0, stream>>>(Wk, Whi + 2048LL*2048, Wlo + 2048LL*2048, 256*1024);
    split_f16<<<1024, blk, 0, stream>>>(Wv, Whi + 2560LL*2048, Wlo + 2560LL*2048, 256*1024);
    split_f16<<<4096, blk, 0, stream>>>(Wo, Wo_hi, Wo_lo, 1024*1024);

    // 1) merged QKV projection -> integer codes f16 [S][3072]
    gemm_f16<2,2,false><<<dim3(NQKV/BN, S_LEN/BM, 1), blk, 0, stream>>>(
        hs_hi, hs_lo, HID_DIM, 0, Whi, Wlo, HID_DIM, 0, 1,
        qkvcode, NQKV, 0, HID_DIM, 1.f, nullptr, nullptr, nullptr,
        3, s_q, s_k, s_v, 0, 0);

    // 2) RoPE (code units) -> hi/lo planes; v codes -> [kvh][HD][S]
    rope_f16<<<(NH*S_LEN*HD)/256, blk, 0, stream>>>(qkvcode, NQKV, 0, cosT, sinT, qr_hi, qr_lo, NH);
    rope_f16<<<(NKVH*S_LEN*HD)/256, blk, 0, stream>>>(qkvcode, NQKV, 2048, cosT, sinT, kr_hi, kr_lo, NKVH);
    transpose_vf16<<<dim3(S_LEN/64, HD/64, NKVH), blk, 0, stream>>>(qkvcode, vT);

    // 3) LDS-free direct-fragment scores + PSM partials -> pml
    scores_direct<<<dim3(S_LEN/BN, S_LEN/BM, NH), blk, 0, stream>>>(
        qr_hi, qr_lo, kr_hi, kr_lo, attn, pml, s_q, s_k);

    // 4) combine partials -> per-row (m, l)
    reduce_ml<<<(NH*S_LEN)/256, blk, 0, stream>>>(pml, fml);

    // 5) streaming finalize: quantized attn f32 in place (+ zero upper tri)
    finalize_quant<<<NH*S_LEN, blk, 0, stream>>>(attn, fml, s_at);

    // 6) PV: attn(f32->codes inline) x vT codes, exact; ao codes f16 out
    gemm_f16<1,1,true><<<dim3(1, S_LEN/BM, NH), blk, 0, stream>>>(
        attn, nullptr, S_LEN, (long long)S_LEN*S_LEN,
        vT, nullptr, S_LEN, (long long)HD*S_LEN, NH/NKVH,
        ao, QD, HD,
        S_LEN, 1.f, s_at, s_v, s_at, 2, s_out, nullptr, nullptr, 0, 1);

    // 7) out = (ao codes @ Wo^T) * s_out, 2-pass (A exact)
    gemm_f16<1,2,false><<<dim3(HID_DIM/BN, S_LEN/BM, 1), blk, 0, stream>>>(
        ao, nullptr, QD, 0, Wo_hi, Wo_lo, QD, 0, 1,
        out, HID_DIM, 0, QD, 1.f, s_out, nullptr, nullptr,
        0, nullptr, nullptr, nullptr, 0, 0);
}

// Round 11
// 504.093 us; speedup vs baseline: 1.1446x; 1.1446x over previous
//
#include <hip/hip_runtime.h>
#include <math.h>

#define S_LEN 2048
#define HID_DIM 2048
#define NH 16
#define NKVH 4
#define HD 128
#define QD (NH*HD)    // 2048
#define KD (NKVH*HD)  // 512
#define NQKV 3072     // Q(2048) | K(512) | V(512)

typedef _Float16 half8_t __attribute__((ext_vector_type(8)));
typedef _Float16 half4_t __attribute__((ext_vector_type(4)));
typedef float f32x4 __attribute__((ext_vector_type(4)));

#define BM 128
#define BN 128
#define BK 32

typedef const __attribute__((address_space(1))) char gas_char;
typedef __attribute__((address_space(3))) char las_char;
#define GL16(gp, lp) __builtin_amdgcn_global_load_lds((gas_char*)(gp), (las_char*)(lp), 16, 0, 0)

// ---------------------------------------------------------------------------
// f16-plane MFMA GEMM, NT (verified rounds 5-10). Passes: Ahi*Bhi
// [+ Ahi*Blo if LB==2][+ Alo*Bhi if LA==2]. AF32: A f32 -> exact codes.
// qmode: 0 f32 store; 1 sym code f16; 2 asym code f16; 3 sym, scale by n0.
// ---------------------------------------------------------------------------
template<int LA, int LB, bool AF32>
__global__ __launch_bounds__(256)
void gemm_f16(const void* __restrict__ Ap, const _Float16* __restrict__ Alo,
              int lda, long long strA,
              const _Float16* __restrict__ Bhi, const _Float16* __restrict__ Blo,
              int ldb, long long strB, int divB,
              void* __restrict__ Cp, int ldc, long long strC,
              int K, float scale_c, const float* sc1, const float* sc2,
              const float* preAp,
              int qmode, const float* q1, const float* q2, const float* q3,
              int causal, int triK)
{
    int bz = blockIdx.z;
    int m0 = blockIdx.y * BM, n0 = blockIdx.x * BN;
    if (causal && n0 > m0 + (BM - 1)) return;
    int Keff = K;
    if (triK && (m0 + BM) < Keff) Keff = m0 + BM;

    const _Float16* Ahi = AF32 ? nullptr : (const _Float16*)Ap + bz * strA;
    const _Float16* AloP = (LA == 2) ? Alo + bz * strA : nullptr;
    const float* Af = AF32 ? (const float*)Ap + bz * strA : nullptr;
    const _Float16* BhiP = Bhi + (long long)(bz / divB) * strB;
    const _Float16* BloP = (LB == 2) ? Blo + (long long)(bz / divB) * strB : nullptr;
    float* Cf = (float*)Cp + bz * strC;
    _Float16* Ch = (_Float16*)Cp + bz * strC;

    float preA = 1.f;
    if (AF32) preA = 1.f / fabsf(preAp[0]);

    __shared__ _Float16 lds[(LA + LB) * 4096];
    _Float16* As0 = lds;
    _Float16* As1 = lds + 4096;
    _Float16* Bs0 = lds + LA * 4096;
    _Float16* Bs1 = lds + (LA + 1) * 4096;

    int t = threadIdx.x;
    int srow = t >> 2;
    int gsw = (srow >> 1) & 3;
    int gc = ((t & 3) ^ gsw) * 8;
    int w = t >> 6, lane = t & 63;
    int wm = (w >> 1) * 64, wn = (w & 1) * 64;
    int lr = lane & 15, lg = lane >> 4;
    int fco = ((lg ^ ((lr >> 1) & 3))) * 8;

    f32x4 acc[4][4];
    #pragma unroll
    for (int i = 0; i < 4; ++i)
        #pragma unroll
        for (int j = 0; j < 4; ++j)
            acc[i][j] = (f32x4){0.f, 0.f, 0.f, 0.f};

    for (int k0 = 0; k0 < Keff; k0 += BK) {
        f32x4 aF[2][2];
        if constexpr (AF32) {
            #pragma unroll
            for (int rep = 0; rep < 2; ++rep) {
                long long ai = (long long)(m0 + rep * 64 + srow) * lda + k0 + gc;
                aF[rep][0] = *(const f32x4*)&Af[ai];
                aF[rep][1] = *(const f32x4*)&Af[ai + 4];
            }
        }
        __syncthreads();
        #pragma unroll
        for (int rep = 0; rep < 2; ++rep) {
            int row = rep * 64 + srow;
            int lo = rep * 2048 + t * 8;
            if constexpr (!AF32) {
                long long ai = (long long)(m0 + row) * lda + k0 + gc;
                GL16(Ahi + ai, As0 + lo);
                if constexpr (LA == 2) GL16(AloP + ai, As1 + lo);
            }
            long long bi = (long long)(n0 + row) * ldb + k0 + gc;
            GL16(BhiP + bi, Bs0 + lo);
            if constexpr (LB == 2) GL16(BloP + bi, Bs1 + lo);
        }
        if constexpr (AF32) {
            #pragma unroll
            for (int rep = 0; rep < 2; ++rep) {
                half8_t h;
                #pragma unroll
                for (int e = 0; e < 4; ++e) {
                    h[e]     = (_Float16)(aF[rep][0][e] * preA);
                    h[e + 4] = (_Float16)(aF[rep][1][e] * preA);
                }
                *(half8_t*)&As0[rep * 2048 + t * 8] = h;
            }
        }
        __syncthreads();

        half8_t a0[4], b0[4];
        #pragma unroll
        for (int i = 0; i < 4; ++i) a0[i] = *(const half8_t*)&As0[(wm + i*16 + lr) * 32 + fco];
        #pragma unroll
        for (int j = 0; j < 4; ++j) b0[j] = *(const half8_t*)&Bs0[(wn + j*16 + lr) * 32 + fco];
        #pragma unroll
        for (int i = 0; i < 4; ++i)
            #pragma unroll
            for (int j = 0; j < 4; ++j)
                acc[i][j] = __builtin_amdgcn_mfma_f32_16x16x32_f16(a0[i], b0[j], acc[i][j], 0, 0, 0);
        if constexpr (LB == 2) {
            half8_t b1[4];
            #pragma unroll
            for (int j = 0; j < 4; ++j) b1[j] = *(const half8_t*)&Bs1[(wn + j*16 + lr) * 32 + fco];
            #pragma unroll
            for (int i = 0; i < 4; ++i)
                #pragma unroll
                for (int j = 0; j < 4; ++j)
                    acc[i][j] = __builtin_amdgcn_mfma_f32_16x16x32_f16(a0[i], b1[j], acc[i][j], 0, 0, 0);
        }
        if constexpr (LA == 2) {
            half8_t a1[4];
            #pragma unroll
            for (int i = 0; i < 4; ++i) a1[i] = *(const half8_t*)&As1[(wm + i*16 + lr) * 32 + fco];
            #pragma unroll
            for (int i = 0; i < 4; ++i)
                #pragma unroll
                for (int j = 0; j < 4; ++j)
                    acc[i][j] = __builtin_amdgcn_mfma_f32_16x16x32_f16(a1[i], b0[j], acc[i][j], 0, 0, 0);
        }
    }

    float se = scale_c;
    if (sc1) se *= fabsf(sc1[0]);
    if (sc2) se *= fabsf(sc2[0]);
    float sv = 1.f;
    if (qmode == 3) {
        const float* sp = (n0 < 2048) ? q1 : ((n0 < 2560) ? q2 : q3);
        sv = fabsf(sp[0]);
        qmode = 1;
    } else if (qmode) {
        sv = fabsf(q1[0]);
    }

    #pragma unroll
    for (int i = 0; i < 4; ++i)
        #pragma unroll
        for (int j = 0; j < 4; ++j)
            #pragma unroll
            for (int r = 0; r < 4; ++r) {
                long long row = m0 + wm + i * 16 + lg * 4 + r;
                long long col = n0 + wn + j * 16 + lr;
                float v = acc[i][j][r] * se;
                if (qmode == 0) {
                    Cf[row * (long long)ldc + col] = v;
                } else if (qmode == 1) {
                    float u = rintf(fminf(fmaxf(v / sv, -128.f), 127.f));
                    Ch[row * (long long)ldc + col] = (_Float16)u;
                } else {
                    float u = rintf(fminf(fmaxf(v / sv, 0.f), 255.f));
                    Ch[row * (long long)ldc + col] = (_Float16)u;
                }
            }
}

// ---------------------------------------------------------------------------
// Scores GEMM (K=HD=128, NT, f16 hi/lo planes, 3 passes) with:
//  - round-9 LDS staging structure (verified)
//  - PSM partial (max, sumexp) epilogue using fast __expf
//  - COALESCED f32 stores: acc is transposed through a padded LDS tile
//    (float[64][132]) per 64-row half, then whole 512-B rows stored as f32x4.
// ---------------------------------------------------------------------------
__global__ __launch_bounds__(256)
void scores_gemm(const _Float16* __restrict__ qhi, const _Float16* __restrict__ qlo,
                 const _Float16* __restrict__ khi, const _Float16* __restrict__ klo,
                 float* __restrict__ attn, float* __restrict__ pml,
                 const float* sq_p, const float* sk_p)
{
    int m0 = blockIdx.y * BM, n0 = blockIdx.x * BN;
    if (n0 > m0 + (BM - 1)) return;
    int h = blockIdx.z;

    const _Float16* Ahi = qhi + (long long)h * S_LEN * HD;
    const _Float16* Alo = qlo + (long long)h * S_LEN * HD;
    const _Float16* Bhi = khi + (long long)(h >> 2) * S_LEN * HD;
    const _Float16* Blo = klo + (long long)(h >> 2) * S_LEN * HD;
    float* S = attn + (long long)h * S_LEN * S_LEN;

    float se = fabsf(sq_p[0]) * fabsf(sk_p[0]) * 0.08838834764831845f;

    // 33792 B shared: staging (4 planes x 8KB = 32KB) unioned with the
    // f32[64][132] transpose tile (33792 B).
    __shared__ float lds_f[8448];
    _Float16* As0 = (_Float16*)lds_f;
    _Float16* As1 = As0 + 4096;
    _Float16* Bs0 = As0 + 8192;
    _Float16* Bs1 = As0 + 12288;

    int t = threadIdx.x;
    int srow = t >> 2;
    int gsw = (srow >> 1) & 3;
    int gc = ((t & 3) ^ gsw) * 8;
    int w = t >> 6, lane = t & 63;
    int wm = (w >> 1) * 64, wn = (w & 1) * 64;
    int lr = lane & 15, lg = lane >> 4;
    int fco = ((lg ^ ((lr >> 1) & 3))) * 8;

    f32x4 acc[4][4];
    #pragma unroll
    for (int i = 0; i < 4; ++i)
        #pragma unroll
        for (int j = 0; j < 4; ++j)
            acc[i][j] = (f32x4){0.f, 0.f, 0.f, 0.f};

    for (int k0 = 0; k0 < HD; k0 += BK) {
        __syncthreads();
        #pragma unroll
        for (int rep = 0; rep < 2; ++rep) {
            int row = rep * 64 + srow;
            int lo = rep * 2048 + t * 8;
            long long ai = (long long)(m0 + row) * HD + k0 + gc;
            long long bi = (long long)(n0 + row) * HD + k0 + gc;
            GL16(Ahi + ai, As0 + lo);
            GL16(Alo + ai, As1 + lo);
            GL16(Bhi + bi, Bs0 + lo);
            GL16(Blo + bi, Bs1 + lo);
        }
        __syncthreads();

        half8_t a0[4], b0[4], a1[4], b1[4];
        #pragma unroll
        for (int i = 0; i < 4; ++i) {
            a0[i] = *(const half8_t*)&As0[(wm + i*16 + lr) * 32 + fco];
            a1[i] = *(const half8_t*)&As1[(wm + i*16 + lr) * 32 + fco];
        }
        #pragma unroll
        for (int j = 0; j < 4; ++j) {
            b0[j] = *(const half8_t*)&Bs0[(wn + j*16 + lr) * 32 + fco];
            b1[j] = *(const half8_t*)&Bs1[(wn + j*16 + lr) * 32 + fco];
        }
        #pragma unroll
        for (int i = 0; i < 4; ++i)
            #pragma unroll
            for (int j = 0; j < 4; ++j)
                acc[i][j] = __builtin_amdgcn_mfma_f32_16x16x32_f16(a0[i], b0[j], acc[i][j], 0, 0, 0);
        #pragma unroll
        for (int i = 0; i < 4; ++i)
            #pragma unroll
            for (int j = 0; j < 4; ++j)
                acc[i][j] = __builtin_amdgcn_mfma_f32_16x16x32_f16(a0[i], b1[j], acc[i][j], 0, 0, 0);
        #pragma unroll
        for (int i = 0; i < 4; ++i)
            #pragma unroll
            for (int j = 0; j < 4; ++j)
                acc[i][j] = __builtin_amdgcn_mfma_f32_16x16x32_f16(a1[i], b0[j], acc[i][j], 0, 0, 0);
    }

    // ---- PSM: per-(row, 64col-half) causal-masked (max, sumexp) partials
    int cb64 = (n0 + wn) >> 6;
    #pragma unroll
    for (int i = 0; i < 4; ++i)
        #pragma unroll
        for (int r = 0; r < 4; ++r) {
            int row = m0 + wm + i * 16 + lg * 4 + r;
            float vv[4];
            float mloc = -INFINITY;
            #pragma unroll
            for (int j = 0; j < 4; ++j) {
                int col = n0 + wn + j * 16 + lr;
                float v = acc[i][j][r] * se;
                vv[j] = (col <= row) ? v : -INFINITY;
                mloc = fmaxf(mloc, vv[j]);
            }
            #pragma unroll
            for (int o = 1; o < 16; o <<= 1) mloc = fmaxf(mloc, __shfl_xor(mloc, o));
            float sloc = 0.f;
            #pragma unroll
            for (int j = 0; j < 4; ++j) sloc += __expf(vv[j] - mloc);
            #pragma unroll
            for (int o = 1; o < 16; o <<= 1) sloc += __shfl_xor(sloc, o);
            if (lr == 0) {
                long long idx = (((long long)h * S_LEN + row) * 32 + cb64) * 2;
                pml[idx] = mloc;
                pml[idx + 1] = sloc;
            }
        }

    // ---- coalesced raw-score store via LDS transpose (two 64-row halves)
    int r_own = wm >> 6;                 // 0 or 1: which half this wave holds
    int lrow = t >> 5;                   // 0..7
    int lcol = (t & 31) * 4;             // 0..124
    #pragma unroll
    for (int half = 0; half < 2; ++half) {
        __syncthreads();                 // staging reads done / prior half stored
        if (r_own == half) {
            #pragma unroll
            for (int i = 0; i < 4; ++i)
                #pragma unroll
                for (int j = 0; j < 4; ++j)
                    #pragma unroll
                    for (int r = 0; r < 4; ++r)
                        lds_f[(i * 16 + lg * 4 + r) * 132 + wn + j * 16 + lr] = acc[i][j][r] * se;
        }
        __syncthreads();
        #pragma unroll
        for (int it = 0; it < 8; ++it) {
            int row = it * 8 + lrow;
            f32x4 v = *(const f32x4*)&lds_f[row * 132 + lcol];
            *(f32x4*)&S[(long long)(m0 + half * 64 + row) * S_LEN + n0 + lcol] = v;
        }
    }
}

// ---------------------------------------------------------------------------
// Reduce per-64col partials -> per-row (max, sum)
// ---------------------------------------------------------------------------
__global__ __launch_bounds__(256)
void reduce_ml(const float* __restrict__ pml, float* __restrict__ fml)
{
    int id = blockIdx.x * 256 + threadIdx.x;   // h*S + r
    int r = id & (S_LEN - 1);
    int nb = (r >> 6) + 1;
    float m = -INFINITY, l = 0.f;
    const float* p = pml + (long long)id * 64;
    for (int cb = 0; cb < nb; ++cb) {
        float mp = p[cb * 2], lp = p[cb * 2 + 1];
        float mn = fmaxf(m, mp);
        l = l * __expf(m - mn) + lp * __expf(mp - mn);
        m = mn;
    }
    fml[id * 2] = m;
    fml[id * 2 + 1] = l;
}

// ---------------------------------------------------------------------------
// Streaming softmax finalize + LSQ(asym) in place; reads only the causal
// region, writes full row incl. zero upper triangle.
// ---------------------------------------------------------------------------
__global__ __launch_bounds__(256)
void finalize_quant(float* __restrict__ attn, const float* __restrict__ fml,
                    const float* __restrict__ s_at_p)
{
    int row = blockIdx.x;            // h*S + q
    int q = row & (S_LEN - 1);
    float* p = attn + (long long)row * S_LEN;
    float m = fml[row * 2];
    float l = fml[row * 2 + 1];
    float sa = fabsf(s_at_p[0]);
    int t = threadIdx.x;
    int n4 = (q + 4) & ~3;           // first x4 boundary past q
    for (int c = t * 4; c < n4; c += 1024) {
        f32x4 v = *(const f32x4*)&p[c];
        f32x4 o;
        #pragma unroll
        for (int e = 0; e < 4; ++e) {
            float u = 0.f;
            if (c + e <= q) {
                float pr = __expf(v[e] - m) / l;
                u = rintf(fminf(fmaxf(pr / sa, 0.f), 255.f));
            }
            o[e] = u * sa;
        }
        *(f32x4*)&p[c] = o;
    }
    f32x4 z = (f32x4){0.f, 0.f, 0.f, 0.f};
    for (int c = n4 + t * 4; c < S_LEN; c += 1024)
        *(f32x4*)&p[c] = z;
}

// ---------------------------------------------------------------------------
// f32 -> f16 hi/lo split
// ---------------------------------------------------------------------------
__global__ void split_f16(const float* __restrict__ in, _Float16* __restrict__ hi,
                          _Float16* __restrict__ lo, int n4)
{
    int i = blockIdx.x * 256 + threadIdx.x;
    if (i >= n4) return;
    f32x4 v = ((const f32x4*)in)[i];
    half4_t h, l;
    #pragma unroll
    for (int e = 0; e < 4; ++e) {
        h[e] = (_Float16)v[e];
        l[e] = (_Float16)(v[e] - (float)h[e]);
    }
    ((half4_t*)hi)[i] = h;
    ((half4_t*)lo)[i] = l;
}

// ---------------------------------------------------------------------------
// RoPE on integer codes (strided source) -> hi/lo f16 planes: [nh][S][HD]
// ---------------------------------------------------------------------------
__global__ void rope_f16(const _Float16* __restrict__ codes, int ldc_, int colOff,
                         const float* __restrict__ cosT,
                         const float* __restrict__ sinT,
                         _Float16* __restrict__ ohi, _Float16* __restrict__ olo, int nh)
{
    long long idx = (long long)blockIdx.x * 256 + threadIdx.x;
    int d = idx & (HD - 1);
    long long tt = idx >> 7;     // s*nh + h
    int h = (int)(tt % nh);
    int s = (int)(tt / nh);
    long long base = (long long)s * ldc_ + colOff + h * HD;
    float x = (float)codes[base + d];
    float other = (d < 64) ? -(float)codes[base + d + 64] : (float)codes[base + d - 64];
    float o = x * cosT[s * HD + d] + other * sinT[s * HD + d];
    _Float16 hf = (_Float16)o;
    long long oi = ((long long)h * S_LEN + s) * HD + d;
    ohi[oi] = hf;
    olo[oi] = (_Float16)(o - (float)hf);
}

// ---------------------------------------------------------------------------
// v codes transpose: qkvcode[S][3072] cols 2560.. -> vT [kvh][HD][S]
// ---------------------------------------------------------------------------
__global__ __launch_bounds__(256)
void transpose_vf16(const _Float16* __restrict__ in, _Float16* __restrict__ outp)
{
    __shared__ _Float16 tile[64][72];
    int s0 = blockIdx.x * 64, d0 = blockIdx.y * 64, h = blockIdx.z;
    int t = threadIdx.x;
    int rr = t >> 4, cc = (t & 15) * 4;
    #pragma unroll
    for (int r = 0; r < 4; ++r) {
        half4_t v = *(const half4_t*)&in[(long long)(s0 + rr + 16*r) * NQKV + 2560 + h * HD + d0 + cc];
        *(half4_t*)&tile[rr + 16*r][cc] = v;
    }
    __syncthreads();
    #pragma unroll
    for (int r = 0; r < 4; ++r) {
        int dr = rr + 16 * r;
        half4_t o = { tile[cc+0][dr], tile[cc+1][dr], tile[cc+2][dr], tile[cc+3][dr] };
        *(half4_t*)&outp[((long long)h * HD + d0 + dr) * S_LEN + s0 + cc] = o;
    }
}

extern "C" void kernel_launch(void* const* d_in, const int* in_sizes, int n_in,
                              void* d_out, int out_size, void* d_ws, size_t ws_size,
                              hipStream_t stream)
{
    const float* hs    = (const float*)d_in[0];
    const float* Wq    = (const float*)d_in[1];
    const float* Wk    = (const float*)d_in[2];
    const float* Wv    = (const float*)d_in[3];
    const float* Wo    = (const float*)d_in[4];
    const float* s_q   = (const float*)d_in[5];
    const float* s_k   = (const float*)d_in[6];
    const float* s_v   = (const float*)d_in[7];
    const float* s_at  = (const float*)d_in[8];
    const float* s_out = (const float*)d_in[9];
    const float* cosT  = (const float*)d_in[10];
    const float* sinT  = (const float*)d_in[11];
    // d_in[12] = attention_mask: pure causal, applied structurally.

    float* out  = (float*)d_out;                         // [S][2048]
    float* attn = out + (long long)S_LEN * HID_DIM;      // [16][S][S]

    const long long M1 = 1LL * 1024 * 1024;
    const long long M4 = 4LL * M1;
    const long long M6 = 6LL * M1;

    // ws (46 MB): planes that must survive past the scores GEMM.
    _Float16* wsh   = (_Float16*)d_ws;
    _Float16* qr_hi = wsh;            // 4M
    _Float16* qr_lo = qr_hi + M4;     // 4M
    _Float16* kr_hi = qr_lo + M4;     // 1M
    _Float16* kr_lo = kr_hi + M1;     // 1M
    _Float16* vT    = kr_lo + M1;     // 1M
    _Float16* ao    = vT + M1;        // 4M
    _Float16* Wo_hi = ao + M4;        // 4M
    _Float16* Wo_lo = Wo_hi + M4;     // 4M

    // Pre-scores scratch parked inside the attn region (consumed before
    // the scores GEMM overwrites it).
    _Float16* sc      = (_Float16*)attn;
    _Float16* hs_hi   = sc;             // 4M
    _Float16* hs_lo   = hs_hi + M4;
    _Float16* Whi     = hs_lo + M4;     // [3072][2048] = 6M
    _Float16* Wlo     = Whi + M6;
    _Float16* qkvcode = Wlo + M6;       // [S][3072] = 6M

    // Softmax stats parked in the 'out' region (out written only at the end).
    float* pml = out;                       // [NH][S][32][2] = 2M f32
    float* fml = out + 2LL * 1024 * 1024;   // [NH][S][2]

    dim3 blk(256);

    // 0) one-shot f32 -> f16 hi/lo splits (W planes stacked Q|K|V)
    split_f16<<<4096, blk, 0, stream>>>(hs, hs_hi, hs_lo, 1024*1024);
    split_f16<<<4096, blk, 0, stream>>>(Wq, Whi, Wlo, 1024*1024);
    split_f16<<<1024, blk, 0, stream>>>(Wk, Whi + 2048LL*2048, Wlo + 2048LL*2048, 256*1024);
    split_f16<<<1024, blk, 0, stream>>>(Wv, Whi + 2560LL*2048, Wlo + 2560LL*2048, 256*1024);
    split_f16<<<4096, blk, 0, stream>>>(Wo, Wo_hi, Wo_lo, 1024*1024);

    // 1) merged QKV projection -> integer codes f16 [S][3072]
    gemm_f16<2,2,false><<<dim3(NQKV/BN, S_LEN/BM, 1), blk, 0, stream>>>(
        hs_hi, hs_lo, HID_DIM, 0, Whi, Wlo, HID_DIM, 0, 1,
        qkvcode, NQKV, 0, HID_DIM, 1.f, nullptr, nullptr, nullptr,
        3, s_q, s_k, s_v, 0, 0);

    // 2) RoPE (code units) -> hi/lo planes; v codes -> [kvh][HD][S]
    rope_f16<<<(NH*S_LEN*HD)/256, blk, 0, stream>>>(qkvcode, NQKV, 0, cosT, sinT, qr_hi, qr_lo, NH);
    rope_f16<<<(NKVH*S_LEN*HD)/256, blk, 0, stream>>>(qkvcode, NQKV, 2048, cosT, sinT, kr_hi, kr_lo, NKVH);
    transpose_vf16<<<dim3(S_LEN/64, HD/64, NKVH), blk, 0, stream>>>(qkvcode, vT);

    // 3) scores GEMM (LDS staging, coalesced stores) + PSM partials -> pml
    scores_gemm<<<dim3(S_LEN/BN, S_LEN/BM, NH), blk, 0, stream>>>(
        qr_hi, qr_lo, kr_hi, kr_lo, attn, pml, s_q, s_k);

    // 4) combine partials -> per-row (m, l)
    reduce_ml<<<(NH*S_LEN)/256, blk, 0, stream>>>(pml, fml);

    // 5) streaming finalize: quantized attn f32 in place (+ zero upper tri)
    finalize_quant<<<NH*S_LEN, blk, 0, stream>>>(attn, fml, s_at);

    // 6) PV: attn(f32->codes inline) x vT codes, exact; ao codes f16 out
    gemm_f16<1,1,true><<<dim3(1, S_LEN/BM, NH), blk, 0, stream>>>(
        attn, nullptr, S_LEN, (long long)S_LEN*S_LEN,
        vT, nullptr, S_LEN, (long long)HD*S_LEN, NH/NKVH,
        ao, QD, HD,
        S_LEN, 1.f, s_at, s_v, s_at, 2, s_out, nullptr, nullptr, 0, 1);

    // 7) out = (ao codes @ Wo^T) * s_out, 2-pass (A exact)
    gemm_f16<1,2,false><<<dim3(HID_DIM/BN, S_LEN/BM, 1), blk, 0, stream>>>(
        ao, nullptr, QD, 0, Wo_hi, Wo_lo, QD, 0, 1,
        out, HID_DIM, 0, QD, 1.f, s_out, nullptr, nullptr,
        0, nullptr, nullptr, nullptr, 0, 0);
}